// Round 13
// baseline (127.246 us; speedup 1.0000x reference)
//
#include <hip/hip_runtime.h>
#include <hip/hip_bf16.h>

// S=64, C=27. DOTLEN = 8640 floats = 2160 float4/row; state = 320; comb = 640; hidden = 64.
// k1: pristine R4 champion GEMV (2160 blocks).
// tail_fused: all 5 tail stages in ONE dispatch, 1388 co-resident blocks,
// spin-wait on relaxed agent-scope counters (R3-proven, no fences).
// Block map: [0,432) k2a | [432,972) k2b | [972,1292) k3 | [1292,1308) k4a | [1308,1388) k4b

__device__ __forceinline__ float ag_load(const float* p) {
    return __hip_atomic_load(p, __ATOMIC_RELAXED, __HIP_MEMORY_SCOPE_AGENT);
}
__device__ __forceinline__ void ag_store(float* p, float v) {
    __hip_atomic_store(p, v, __ATOMIC_RELAXED, __HIP_MEMORY_SCOPE_AGENT);
}

__device__ __forceinline__ float wave_reduce_sum(float v) {
    v += __shfl_xor(v, 32, 64);
    v += __shfl_xor(v, 16, 64);
    v += __shfl_xor(v, 8, 64);
    v += __shfl_xor(v, 4, 64);
    v += __shfl_xor(v, 2, 64);
    v += __shfl_xor(v, 1, 64);
    return v;
}

__device__ __forceinline__ float fma4s(float4 w, float4 x, float acc) {
    acc = fmaf(w.x, x.x, acc);
    acc = fmaf(w.y, x.y, acc);
    acc = fmaf(w.z, x.z, acc);
    acc = fmaf(w.w, x.w, acc);
    return acc;
}

__device__ __forceinline__ float4 add4(float4 a, float4 b) {
    return make_float4(a.x + b.x, a.y + b.y, a.z + b.z, a.w + b.w);
}

// Block-uniform spin until *c reaches target (tid0 spins, all sync after).
__device__ __forceinline__ void wait_cnt(int* c, int target) {
    if (threadIdx.x == 0) {
        while (__hip_atomic_load(c, __ATOMIC_RELAXED, __HIP_MEMORY_SCOPE_AGENT) < target)
            __builtin_amdgcn_s_sleep(2);
    }
    __syncthreads();
}
// Drain this block's stores (barrier waits vmcnt(0)), then bump counter.
__device__ __forceinline__ void bump_cnt(int* c) {
    __syncthreads();
    if (threadIdx.x == 0)
        __hip_atomic_fetch_add(c, 1, __ATOMIC_RELAXED, __HIP_MEMORY_SCOPE_AGENT);
}

// ---------------------------------------------------------------------------
// k1: agg1[8640] = agg_W1 . leaf_flat + agg_b1. (R4 exact; DO NOT TOUCH)
__global__ void __launch_bounds__(256) k1_gemv(
    const float* __restrict__ W,     // [8640][8640] block-diag rows
    const float* __restrict__ x,     // [27][8640]
    const float* __restrict__ bias,  // [8640]
    float*       __restrict__ y)     // [8640]
{
    const int b    = blockIdx.x;
    const int node = b / 80;
    const int row0 = node * 320 + (b % 80) * 4;
    const int tid  = threadIdx.x;

    const float4* __restrict__ xf  = reinterpret_cast<const float4*>(x) + (size_t)node * 2160;
    const float4* __restrict__ w0p = reinterpret_cast<const float4*>(W) + (size_t)(row0 + 0) * 2160;
    const float4* __restrict__ w1p = reinterpret_cast<const float4*>(W) + (size_t)(row0 + 1) * 2160;
    const float4* __restrict__ w2p = reinterpret_cast<const float4*>(W) + (size_t)(row0 + 2) * 2160;
    const float4* __restrict__ w3p = reinterpret_cast<const float4*>(W) + (size_t)(row0 + 3) * 2160;

    float4 a0 = make_float4(0.f, 0.f, 0.f, 0.f), a1 = a0, a2 = a0, a3 = a0;
    for (int j = tid; j < 2160; j += 256) {
        float4 xv = xf[j];
        float4 w0 = w0p[j];
        float4 w1 = w1p[j];
        float4 w2 = w2p[j];
        float4 w3 = w3p[j];
        a0.x = fmaf(w0.x, xv.x, a0.x); a0.y = fmaf(w0.y, xv.y, a0.y);
        a0.z = fmaf(w0.z, xv.z, a0.z); a0.w = fmaf(w0.w, xv.w, a0.w);
        a1.x = fmaf(w1.x, xv.x, a1.x); a1.y = fmaf(w1.y, xv.y, a1.y);
        a1.z = fmaf(w1.z, xv.z, a1.z); a1.w = fmaf(w1.w, xv.w, a1.w);
        a2.x = fmaf(w2.x, xv.x, a2.x); a2.y = fmaf(w2.y, xv.y, a2.y);
        a2.z = fmaf(w2.z, xv.z, a2.z); a2.w = fmaf(w2.w, xv.w, a2.w);
        a3.x = fmaf(w3.x, xv.x, a3.x); a3.y = fmaf(w3.y, xv.y, a3.y);
        a3.z = fmaf(w3.z, xv.z, a3.z); a3.w = fmaf(w3.w, xv.w, a3.w);
    }
    float s0 = (a0.x + a0.y) + (a0.z + a0.w);
    float s1 = (a1.x + a1.y) + (a1.z + a1.w);
    float s2 = (a2.x + a2.y) + (a2.z + a2.w);
    float s3 = (a3.x + a3.y) + (a3.z + a3.w);
    s0 = wave_reduce_sum(s0);
    s1 = wave_reduce_sum(s1);
    s2 = wave_reduce_sum(s2);
    s3 = wave_reduce_sum(s3);

    __shared__ float red[4][4];
    const int wv = tid >> 6, lane = tid & 63;
    if (lane == 0) { red[wv][0] = s0; red[wv][1] = s1; red[wv][2] = s2; red[wv][3] = s3; }
    __syncthreads();
    if (tid < 4) {
        float v = red[0][tid] + red[1][tid] + red[2][tid] + red[3][tid];
        y[row0 + tid] = v + bias[row0 + tid];
    }
}

// ---------------------------------------------------------------------------
struct TP {
    const float *states1, *uW1_1, *ub1_1, *uW2_1, *ub2_1;
    const float *aggW0, *aggb0;
    const float *state0, *ext;
    const float *uW1_0, *ub1_0, *uW2_0, *ub2_0;
    const float *agg1;                  // ws, from k1 (kernel-boundary coherent)
    float *h1, *ns1, *agg0p, *h0, *out;
    int *cnt;   // [0..26] per-node k2a done; [27] k2b; [28] k3; [29] k4a
};

__global__ void __launch_bounds__(256, 8) tail_fused(TP p) {
    __shared__ __align__(16) float sh[640];
    __shared__ float hsm[64];
    const int b   = blockIdx.x;
    const int tid = threadIdx.x;
    const int wv  = tid >> 6, lane = tid & 63;

    if (b < 432) {
        // ---- k2a: h1[n][k] = relu(W1[n][k,:] @ [states1[n], agg1[n]] + b1) ----
        const int n = b >> 4;
        float4* shf = reinterpret_cast<float4*>(sh);
        const float4* __restrict__ s1f = reinterpret_cast<const float4*>(p.states1) + (size_t)n * 80;
        const float4* __restrict__ a1f = reinterpret_cast<const float4*>(p.agg1) + (size_t)n * 80;
        if (tid < 80)       shf[tid] = s1f[tid];
        else if (tid < 160) shf[tid] = a1f[tid - 80];
        __syncthreads();

        const int k = (b & 15) * 4 + wv;
        const float4* __restrict__ Wf = reinterpret_cast<const float4*>(p.uW1_1) + ((size_t)n * 64 + k) * 160;
        float acc = 0.f;
        #pragma unroll
        for (int j = lane; j < 160; j += 64)
            acc = fma4s(Wf[j], shf[j], acc);
        acc = wave_reduce_sum(acc);
        if (lane == 0)
            ag_store(p.h1 + n * 64 + k, fmaxf(acc + p.ub1_1[n * 64 + k], 0.f));
        bump_cnt(&p.cnt[n]);
    } else if (b < 972) {
        // ---- k2b: ns1 rows; block t handles rows t*16..t*16+15 (node n = t/20) ----
        const int t = b - 432;
        const int n = t / 20;
        wait_cnt(&p.cnt[n], 16);
        const int base = t * 16;
        float hv = ag_load(p.h1 + n * 64 + lane);
        #pragma unroll
        for (int rr = 0; rr < 4; ++rr) {
            const int row = base + wv * 4 + rr;
            float acc = p.uW2_1[(size_t)row * 64 + lane] * hv;
            acc = wave_reduce_sum(acc);
            if (lane == 0)
                ag_store(p.ns1 + row, p.states1[row] + acc + p.ub2_1[row]);
        }
        bump_cnt(&p.cnt[27]);
    } else if (b < 1292) {
        // ---- k3: agg0 partials agg0p[cs][320] over col-slices of W0 @ ns1 ----
        wait_cnt(&p.cnt[27], 540);
        const int t  = b - 972;
        const int cs = t / 80;
        const int r0 = (t % 80) * 4;
        const float4* __restrict__ w0p = reinterpret_cast<const float4*>(p.aggW0) + (size_t)(r0 + 0) * 2160;
        const float4* __restrict__ w1p = reinterpret_cast<const float4*>(p.aggW0) + (size_t)(r0 + 1) * 2160;
        const float4* __restrict__ w2p = reinterpret_cast<const float4*>(p.aggW0) + (size_t)(r0 + 2) * 2160;
        const float4* __restrict__ w3p = reinterpret_cast<const float4*>(p.aggW0) + (size_t)(r0 + 3) * 2160;

        float a0 = 0.f, a1 = 0.f, a2 = 0.f, a3 = 0.f;
        const int jend = cs * 540 + 540;
        for (int j = cs * 540 + tid; j < jend; j += 256) {
            float x0 = ag_load(p.ns1 + 4 * j);
            float x1 = ag_load(p.ns1 + 4 * j + 1);
            float x2 = ag_load(p.ns1 + 4 * j + 2);
            float x3 = ag_load(p.ns1 + 4 * j + 3);
            float4 w0 = w0p[j];
            float4 w1 = w1p[j];
            float4 w2 = w2p[j];
            float4 w3 = w3p[j];
            a0 = fmaf(w0.x, x0, fmaf(w0.y, x1, fmaf(w0.z, x2, fmaf(w0.w, x3, a0))));
            a1 = fmaf(w1.x, x0, fmaf(w1.y, x1, fmaf(w1.z, x2, fmaf(w1.w, x3, a1))));
            a2 = fmaf(w2.x, x0, fmaf(w2.y, x1, fmaf(w2.z, x2, fmaf(w2.w, x3, a2))));
            a3 = fmaf(w3.x, x0, fmaf(w3.y, x1, fmaf(w3.z, x2, fmaf(w3.w, x3, a3))));
        }
        a0 = wave_reduce_sum(a0);
        a1 = wave_reduce_sum(a1);
        a2 = wave_reduce_sum(a2);
        a3 = wave_reduce_sum(a3);
        if (lane == 0) {
            hsm[wv * 4 + 0] = a0; hsm[wv * 4 + 1] = a1;
            hsm[wv * 4 + 2] = a2; hsm[wv * 4 + 3] = a3;
        }
        __syncthreads();
        if (tid < 4) {
            float v = hsm[tid] + hsm[4 + tid] + hsm[8 + tid] + hsm[12 + tid];
            ag_store(p.agg0p + cs * 320 + r0 + tid, v);
        }
        bump_cnt(&p.cnt[28]);
    } else if (b < 1308) {
        // ---- k4a: h0[64] = relu(W1_0 @ [state0+ext, sum(agg0p)+b0] + b1_0) ----
        wait_cnt(&p.cnt[28], 320);
        for (int j = tid; j < 320; j += 256) {
            sh[j]       = p.state0[j] + p.ext[j];
            sh[320 + j] = ag_load(p.agg0p + j) + ag_load(p.agg0p + 320 + j)
                        + ag_load(p.agg0p + 640 + j) + ag_load(p.agg0p + 960 + j)
                        + p.aggb0[j];
        }
        __syncthreads();
        const float4* __restrict__ cf = reinterpret_cast<const float4*>(sh);
        const int k = (b - 1292) * 4 + wv;   // 0..63
        const float4* __restrict__ Wf = reinterpret_cast<const float4*>(p.uW1_0) + (size_t)k * 160;
        float acc = 0.f;
        #pragma unroll
        for (int j = lane; j < 160; j += 64)
            acc = fma4s(Wf[j], cf[j], acc);
        acc = wave_reduce_sum(acc);
        if (lane == 0)
            ag_store(p.h0 + k, fmaxf(acc + p.ub1_0[k], 0.f));
        bump_cnt(&p.cnt[29]);
    } else {
        // ---- k4b: out[i] = (state0+ext)[i] + W2_0[i,:] @ h0 + b2_0[i] ----
        wait_cnt(&p.cnt[29], 16);
        const int i = (b - 1308) * 4 + wv;   // 0..319
        float acc = p.uW2_0[(size_t)i * 64 + lane] * ag_load(p.h0 + lane);
        acc = wave_reduce_sum(acc);
        if (lane == 0)
            p.out[i] = p.state0[i] + p.ext[i] + acc + p.ub2_0[i];
    }
}

extern "C" void kernel_launch(void* const* d_in, const int* in_sizes, int n_in,
                              void* d_out, int out_size, void* d_ws, size_t ws_size,
                              hipStream_t stream) {
    float* ws = (float*)d_ws;

    TP p;
    p.states1 = (const float*)d_in[2];
    p.uW1_1   = (const float*)d_in[12];
    p.ub1_1   = (const float*)d_in[13];
    p.uW2_1   = (const float*)d_in[14];
    p.ub2_1   = (const float*)d_in[15];
    p.aggW0   = (const float*)d_in[4];
    p.aggb0   = (const float*)d_in[5];
    p.state0  = (const float*)d_in[1];
    p.ext     = (const float*)d_in[0];
    p.uW1_0   = (const float*)d_in[8];
    p.ub1_0   = (const float*)d_in[9];
    p.uW2_0   = (const float*)d_in[10];
    p.ub2_0   = (const float*)d_in[11];
    p.agg1    = ws;                 // 8640
    p.h1      = ws + 8640;          // 1728
    p.ns1     = ws + 10368;         // 8640
    p.agg0p   = ws + 19008;         // 1280
    p.h0      = ws + 20288;         // 64
    p.out     = (float*)d_out;
    p.cnt     = (int*)(ws + 20352); // 30 ints

    // zero spin counters each replay (graph-capturable memset node)
    hipMemsetAsync(p.cnt, 0, 30 * sizeof(int), stream);

    k1_gemv<<<2160, 256, 0, stream>>>((const float*)d_in[6], (const float*)d_in[3],
                                      (const float*)d_in[7], (float*)p.agg1);
    tail_fused<<<1388, 256, 0, stream>>>(p);
}

// Round 14
// 91.347 us; speedup vs baseline: 1.3930x; 1.3930x over previous
//
#include <hip/hip_runtime.h>
#include <hip/hip_bf16.h>

// S=64, C=27. DOTLEN = 8640 floats = 2160 float4/row; state = 320; comb = 640; hidden = 64.
// Chain: k1 (R4-exact GEMV) -> k2_fused (h + ns1, 540 blocks) -> k3 (R4-exact)
// -> k4_fused (root h + out, 80 blocks). No cross-block sync anywhere.
// Anti-serial-round rule (R8/R11): waves computing 16 h-dots issue ALL 48
// loads into independent accumulators first, then do 16 reduces.

__device__ __forceinline__ float wave_reduce_sum(float v) {
    v += __shfl_xor(v, 32, 64);
    v += __shfl_xor(v, 16, 64);
    v += __shfl_xor(v, 8, 64);
    v += __shfl_xor(v, 4, 64);
    v += __shfl_xor(v, 2, 64);
    v += __shfl_xor(v, 1, 64);
    return v;
}

__device__ __forceinline__ float fma4s(float4 w, float4 x, float acc) {
    acc = fmaf(w.x, x.x, acc);
    acc = fmaf(w.y, x.y, acc);
    acc = fmaf(w.z, x.z, acc);
    acc = fmaf(w.w, x.w, acc);
    return acc;
}

__device__ __forceinline__ float4 add4(float4 a, float4 b) {
    return make_float4(a.x + b.x, a.y + b.y, a.z + b.z, a.w + b.w);
}

// All-16-dots-one-round: wave `wv` computes h[wv*16 .. wv*16+15] of
// relu(W1[64][640] @ comb + b1), comb staged as float4* cf. Writes h to hsm.
__device__ __forceinline__ void h_dots_one_round(
    const float4* __restrict__ Wbase,   // W1 as float4 rows of 160
    const float4* __restrict__ cf,      // comb [160 float4]
    const float* __restrict__ b1,       // bias [64]
    float* hsm, int wv, int lane)
{
    const float4 z = make_float4(0.f, 0.f, 0.f, 0.f);
    const int kbase = wv * 16;
    float4 x0 = cf[lane];
    float4 x1 = cf[64 + lane];
    float4 x2 = (lane < 32) ? cf[128 + lane] : z;
    float pac[16];
    #pragma unroll
    for (int kk = 0; kk < 16; ++kk) {
        const float4* __restrict__ Wf = Wbase + (size_t)(kbase + kk) * 160;
        float4 w0 = Wf[lane];
        float4 w1 = Wf[64 + lane];
        float4 w2 = (lane < 32) ? Wf[128 + lane] : z;
        float a = 0.f;
        a = fma4s(w0, x0, a);
        a = fma4s(w1, x1, a);
        a = fma4s(w2, x2, a);
        pac[kk] = a;
    }
    #pragma unroll
    for (int kk = 0; kk < 16; ++kk) {
        float s = wave_reduce_sum(pac[kk]);
        if (lane == 0) hsm[kbase + kk] = fmaxf(s + b1[kbase + kk], 0.f);
    }
}

// ---------------------------------------------------------------------------
// k1: agg1[8640] = agg_W1 . leaf_flat + agg_b1. (R4 exact; DO NOT TOUCH)
__global__ void __launch_bounds__(256) k1_gemv(
    const float* __restrict__ W,     // [8640][8640] block-diag rows
    const float* __restrict__ x,     // [27][8640]
    const float* __restrict__ bias,  // [8640]
    float*       __restrict__ y)     // [8640]
{
    const int b    = blockIdx.x;
    const int node = b / 80;
    const int row0 = node * 320 + (b % 80) * 4;
    const int tid  = threadIdx.x;

    const float4* __restrict__ xf  = reinterpret_cast<const float4*>(x) + (size_t)node * 2160;
    const float4* __restrict__ w0p = reinterpret_cast<const float4*>(W) + (size_t)(row0 + 0) * 2160;
    const float4* __restrict__ w1p = reinterpret_cast<const float4*>(W) + (size_t)(row0 + 1) * 2160;
    const float4* __restrict__ w2p = reinterpret_cast<const float4*>(W) + (size_t)(row0 + 2) * 2160;
    const float4* __restrict__ w3p = reinterpret_cast<const float4*>(W) + (size_t)(row0 + 3) * 2160;

    float4 a0 = make_float4(0.f, 0.f, 0.f, 0.f), a1 = a0, a2 = a0, a3 = a0;
    for (int j = tid; j < 2160; j += 256) {
        float4 xv = xf[j];
        float4 w0 = w0p[j];
        float4 w1 = w1p[j];
        float4 w2 = w2p[j];
        float4 w3 = w3p[j];
        a0.x = fmaf(w0.x, xv.x, a0.x); a0.y = fmaf(w0.y, xv.y, a0.y);
        a0.z = fmaf(w0.z, xv.z, a0.z); a0.w = fmaf(w0.w, xv.w, a0.w);
        a1.x = fmaf(w1.x, xv.x, a1.x); a1.y = fmaf(w1.y, xv.y, a1.y);
        a1.z = fmaf(w1.z, xv.z, a1.z); a1.w = fmaf(w1.w, xv.w, a1.w);
        a2.x = fmaf(w2.x, xv.x, a2.x); a2.y = fmaf(w2.y, xv.y, a2.y);
        a2.z = fmaf(w2.z, xv.z, a2.z); a2.w = fmaf(w2.w, xv.w, a2.w);
        a3.x = fmaf(w3.x, xv.x, a3.x); a3.y = fmaf(w3.y, xv.y, a3.y);
        a3.z = fmaf(w3.z, xv.z, a3.z); a3.w = fmaf(w3.w, xv.w, a3.w);
    }
    float s0 = (a0.x + a0.y) + (a0.z + a0.w);
    float s1 = (a1.x + a1.y) + (a1.z + a1.w);
    float s2 = (a2.x + a2.y) + (a2.z + a2.w);
    float s3 = (a3.x + a3.y) + (a3.z + a3.w);
    s0 = wave_reduce_sum(s0);
    s1 = wave_reduce_sum(s1);
    s2 = wave_reduce_sum(s2);
    s3 = wave_reduce_sum(s3);

    __shared__ float red[4][4];
    const int wv = tid >> 6, lane = tid & 63;
    if (lane == 0) { red[wv][0] = s0; red[wv][1] = s1; red[wv][2] = s2; red[wv][3] = s3; }
    __syncthreads();
    if (tid < 4) {
        float v = red[0][tid] + red[1][tid] + red[2][tid] + red[3][tid];
        y[row0 + tid] = v + bias[row0 + tid];
    }
}

// ---------------------------------------------------------------------------
// k2_fused: 540 blocks (27 nodes x 20). Block b: n = b/20, rows b*16..b*16+15.
// Stages comb=[states1[n], agg1[n]], computes full h (redundant per block,
// one-round pattern), then its 16 ns1 rows.
__global__ void __launch_bounds__(256) k2_fused(
    const float* __restrict__ states1,  // [27][320]
    const float* __restrict__ agg1,     // ws [8640]
    const float* __restrict__ W1,       // [27][64][640]
    const float* __restrict__ b1,       // [27][64]
    const float* __restrict__ W2,       // [8640][64]
    const float* __restrict__ b2,       // [8640]
    float*       __restrict__ ns1)      // ws [8640]
{
    __shared__ __align__(16) float sh[640];
    __shared__ float hsm[64];
    const int b   = blockIdx.x;
    const int n   = b / 20;
    const int tid = threadIdx.x;
    const int wv  = tid >> 6, lane = tid & 63;

    float4* shf = reinterpret_cast<float4*>(sh);
    const float4* __restrict__ s1f = reinterpret_cast<const float4*>(states1) + (size_t)n * 80;
    const float4* __restrict__ a1f = reinterpret_cast<const float4*>(agg1) + (size_t)n * 80;
    if (tid < 80)       shf[tid] = s1f[tid];
    else if (tid < 160) shf[tid] = a1f[tid - 80];
    __syncthreads();

    h_dots_one_round(reinterpret_cast<const float4*>(W1) + (size_t)n * 64 * 160,
                     reinterpret_cast<const float4*>(sh),
                     b1 + n * 64, hsm, wv, lane);
    __syncthreads();

    // 16 ns1 rows: 4 rows per wave, loads independent
    const int base = b * 16;
    float hv = hsm[lane];
    #pragma unroll
    for (int rr = 0; rr < 4; ++rr) {
        const int row = base + wv * 4 + rr;
        float acc = W2[(size_t)row * 64 + lane] * hv;
        acc = wave_reduce_sum(acc);
        if (lane == 0) ns1[row] = states1[row] + acc + b2[row];
    }
}

// ---------------------------------------------------------------------------
// k3: agg0 partials: agg0p[cs][320]. (R4 exact, 320 blocks)
__global__ void __launch_bounds__(256) k3_gemv(
    const float* __restrict__ W,    // [320][8640]
    const float* __restrict__ x,    // ns1 [8640] (ws)
    float*       __restrict__ yp)   // [4][320] partials (ws)
{
    const int b   = blockIdx.x;     // 0..319
    const int cs  = b / 80;
    const int r0  = (b % 80) * 4;
    const int tid = threadIdx.x;

    const float4* __restrict__ xf  = reinterpret_cast<const float4*>(x);
    const float4* __restrict__ w0p = reinterpret_cast<const float4*>(W) + (size_t)(r0 + 0) * 2160;
    const float4* __restrict__ w1p = reinterpret_cast<const float4*>(W) + (size_t)(r0 + 1) * 2160;
    const float4* __restrict__ w2p = reinterpret_cast<const float4*>(W) + (size_t)(r0 + 2) * 2160;
    const float4* __restrict__ w3p = reinterpret_cast<const float4*>(W) + (size_t)(r0 + 3) * 2160;

    float4 a0 = make_float4(0.f, 0.f, 0.f, 0.f), a1 = a0, a2 = a0, a3 = a0;
    const int jend = cs * 540 + 540;
    for (int j = cs * 540 + tid; j < jend; j += 256) {
        float4 xv = xf[j];
        float4 w0 = w0p[j];
        float4 w1 = w1p[j];
        float4 w2 = w2p[j];
        float4 w3 = w3p[j];
        a0.x = fmaf(w0.x, xv.x, a0.x); a0.y = fmaf(w0.y, xv.y, a0.y);
        a0.z = fmaf(w0.z, xv.z, a0.z); a0.w = fmaf(w0.w, xv.w, a0.w);
        a1.x = fmaf(w1.x, xv.x, a1.x); a1.y = fmaf(w1.y, xv.y, a1.y);
        a1.z = fmaf(w1.z, xv.z, a1.z); a1.w = fmaf(w1.w, xv.w, a1.w);
        a2.x = fmaf(w2.x, xv.x, a2.x); a2.y = fmaf(w2.y, xv.y, a2.y);
        a2.z = fmaf(w2.z, xv.z, a2.z); a2.w = fmaf(w2.w, xv.w, a2.w);
        a3.x = fmaf(w3.x, xv.x, a3.x); a3.y = fmaf(w3.y, xv.y, a3.y);
        a3.z = fmaf(w3.z, xv.z, a3.z); a3.w = fmaf(w3.w, xv.w, a3.w);
    }
    float s0 = (a0.x + a0.y) + (a0.z + a0.w);
    float s1 = (a1.x + a1.y) + (a1.z + a1.w);
    float s2 = (a2.x + a2.y) + (a2.z + a2.w);
    float s3 = (a3.x + a3.y) + (a3.z + a3.w);
    s0 = wave_reduce_sum(s0);
    s1 = wave_reduce_sum(s1);
    s2 = wave_reduce_sum(s2);
    s3 = wave_reduce_sum(s3);

    __shared__ float red[4][4];
    const int wv = tid >> 6, lane = tid & 63;
    if (lane == 0) { red[wv][0] = s0; red[wv][1] = s1; red[wv][2] = s2; red[wv][3] = s3; }
    __syncthreads();
    if (tid < 4) {
        yp[cs * 320 + r0 + tid] =
            red[0][tid] + red[1][tid] + red[2][tid] + red[3][tid];
    }
}

// ---------------------------------------------------------------------------
// k4_fused: 80 blocks. Each stages comb0, computes full h0 (redundant,
// one-round pattern over L2-hot W1_0), writes its 4 out rows.
__global__ void __launch_bounds__(256) k4_fused(
    const float* __restrict__ state0,  // [320]
    const float* __restrict__ ext,     // [320]
    const float* __restrict__ agg0p,   // ws [4][320]
    const float* __restrict__ aggb0,   // [320]
    const float* __restrict__ W1,      // up_W1_0 [64][640]
    const float* __restrict__ b1,      // [64]
    const float* __restrict__ W2,      // up_W2_0 [320][64]
    const float* __restrict__ b2,      // [320]
    float*       __restrict__ out)     // [320]
{
    __shared__ __align__(16) float sh[640];
    __shared__ float hsm[64];
    const int tid = threadIdx.x;
    const int wv  = tid >> 6, lane = tid & 63;

    float4* shf = reinterpret_cast<float4*>(sh);
    const float4* __restrict__ s0f = reinterpret_cast<const float4*>(state0);
    const float4* __restrict__ exf = reinterpret_cast<const float4*>(ext);
    const float4* __restrict__ p0  = reinterpret_cast<const float4*>(agg0p);
    const float4* __restrict__ b0f = reinterpret_cast<const float4*>(aggb0);
    if (tid < 80) {
        shf[tid] = add4(s0f[tid], exf[tid]);
    } else if (tid < 160) {
        int jj = tid - 80;
        shf[tid] = add4(add4(add4(p0[jj], p0[80 + jj]), add4(p0[160 + jj], p0[240 + jj])), b0f[jj]);
    }
    __syncthreads();

    h_dots_one_round(reinterpret_cast<const float4*>(W1),
                     reinterpret_cast<const float4*>(sh),
                     b1, hsm, wv, lane);
    __syncthreads();

    const int i = blockIdx.x * 4 + wv;   // 0..319
    float acc = W2[(size_t)i * 64 + lane] * hsm[lane];
    acc = wave_reduce_sum(acc);
    if (lane == 0) out[i] = sh[i] + acc + b2[i];
}

extern "C" void kernel_launch(void* const* d_in, const int* in_sizes, int n_in,
                              void* d_out, int out_size, void* d_ws, size_t ws_size,
                              hipStream_t stream) {
    const float* ext      = (const float*)d_in[0];
    const float* state0   = (const float*)d_in[1];
    const float* states1  = (const float*)d_in[2];
    const float* states2  = (const float*)d_in[3];
    const float* agg_W0   = (const float*)d_in[4];
    const float* agg_b0   = (const float*)d_in[5];
    const float* agg_W1   = (const float*)d_in[6];
    const float* agg_b1   = (const float*)d_in[7];
    const float* up_W1_0  = (const float*)d_in[8];
    const float* up_b1_0  = (const float*)d_in[9];
    const float* up_W2_0  = (const float*)d_in[10];
    const float* up_b2_0  = (const float*)d_in[11];
    const float* up_W1_1  = (const float*)d_in[12];
    const float* up_b1_1  = (const float*)d_in[13];
    const float* up_W2_1  = (const float*)d_in[14];
    const float* up_b2_1  = (const float*)d_in[15];

    float* out   = (float*)d_out;
    float* ws    = (float*)d_ws;
    float* agg1  = ws;             // 8640
    float* ns1   = ws + 8640;      // 8640
    float* agg0p = ws + 17280;     // 1280

    k1_gemv <<<2160, 256, 0, stream>>>(agg_W1, states2, agg_b1, agg1);
    k2_fused<<<540,  256, 0, stream>>>(states1, agg1, up_W1_1, up_b1_1, up_W2_1, up_b2_1, ns1);
    k3_gemv <<<320,  256, 0, stream>>>(agg_W0, ns1, agg0p);
    k4_fused<<<80,   256, 0, stream>>>(state0, ext, agg0p, agg_b0,
                                       up_W1_0, up_b1_0, up_W2_0, up_b2_0, out);
}